// Round 10
// baseline (1556.517 us; speedup 1.0000x reference)
//
#include <hip/hip_runtime.h>

#define NNODES 100000
#define NEDGES 1600000
#define HID    128
#define INDIM  64

typedef __attribute__((ext_vector_type(8))) short bf16x8;
typedef __attribute__((ext_vector_type(4))) float f32x4;
typedef __attribute__((ext_vector_type(2))) _Float16 half2_t;
typedef unsigned long long u64;

__device__ __forceinline__ unsigned pack_bf16x2(float a, float b) {
  unsigned ua = __float_as_uint(a), ub = __float_as_uint(b);
  ua = (ua + 0x7fffu + ((ua >> 16) & 1u)) >> 16;
  ub = (ub + 0x7fffu + ((ub >> 16) & 1u)) >> 16;
  return ua | (ub << 16);
}
__device__ __forceinline__ unsigned short bf16r(float x) {
  unsigned u = __float_as_uint(x);
  u = (u + 0x7fffu + ((u >> 16) & 1u)) >> 16;
  return (unsigned short)u;
}
__device__ __forceinline__ float bf16lo(unsigned u) { return __uint_as_float(u << 16); }
__device__ __forceinline__ float bf16hi(unsigned u) { return __uint_as_float(u & 0xffff0000u); }
__device__ __forceinline__ unsigned f16x2(float a, float b) {
  half2_t h; h.x = (_Float16)a; h.y = (_Float16)b;
  return __builtin_bit_cast(unsigned, h);
}

// ============================ fused prep: hist | xprep | wtprep ============================
// Section A (blocks [0,EB)): per-XCD-privatized u32 packed histogram — count [31:25], wdeg
//   Q6.19 [24:0]; L2-resident copies, workgroup-scope atomics. rank[e] = xcc<<8 | local rank.
// Section B: x -> fp16, COLUMN-SHARDED layout (4 shards x 16 cols): shard s holds words
//   [node*8 .. node*8+8) covering cols [16s,16s+16). Section C: W transpose -> bf16 [c][K].

#define XB ((NNODES * INDIM / 4) / 256)                 // 6250
#define WTOT (HID * INDIM + 4 * HID * HID)              // 73728
#define WB ((WTOT + 255) / 256)                         // 288
#define EB ((NEDGES + 255) / 256)                       // 6250
#define NB ((NNODES + 255) / 256)                       // 391

__global__ __launch_bounds__(256) void prep_kernel(const float* __restrict__ x, uint2* __restrict__ xsh,
                                                   const float* __restrict__ W_in, const float* __restrict__ W_mid,
                                                   const float* __restrict__ W_out, unsigned short* __restrict__ wt,
                                                   const int* __restrict__ ei, const float* __restrict__ ew,
                                                   unsigned* __restrict__ packed,
                                                   unsigned short* __restrict__ rank) {
  const int b = blockIdx.x;
  if (b < EB) {
    int e = b * 256 + threadIdx.x;
    if (e < NEDGES) {
      unsigned xcc;
      asm volatile("s_getreg_b32 %0, hwreg(HW_REG_XCC_ID)" : "=s"(xcc));
      xcc &= 7u;
      int d = ei[NEDGES + e];
      unsigned inc = (1u << 25) | (unsigned)(ew[e] * 524288.0f + 0.5f);
      unsigned old = __hip_atomic_fetch_add(&packed[(size_t)xcc * NNODES + d], inc,
                                            __ATOMIC_RELAXED, __HIP_MEMORY_SCOPE_WORKGROUP);
      rank[e] = (unsigned short)((xcc << 8) | (old >> 25));
    }
  } else if (b < EB + XB) {
    int i = (b - EB) * 256 + threadIdx.x;
    float4 v = reinterpret_cast<const float4*>(x)[i];
    int node = i >> 4, j = i & 15;                       // j: which uint2 (cols 4j..4j+4)
    int s = j >> 2;                                      // shard (16 cols each)
    xsh[(size_t)s * (NNODES * 4) + node * 4 + (j & 3)] = make_uint2(f16x2(v.x, v.y), f16x2(v.z, v.w));
  } else {
    int idx = (b - EB - XB) * 256 + threadIdx.x;
    if (idx < WTOT) {
      float v;
      if (idx < HID * INDIM) {
        int c = idx / INDIM, k = idx % INDIM;
        v = W_in[(size_t)k * HID + c];
      } else {
        int r = idx - HID * INDIM;
        int l = r / (HID * HID), j = r % (HID * HID);
        int c = j / HID, k = j % HID;
        const float* W = (l < 3) ? (W_mid + (size_t)l * HID * HID) : W_out;
        v = W[(size_t)k * HID + c];
      }
      wt[idx] = bf16r(v);
    }
  }
}

// ============================ scans ============================
// scan1: reduce 8 XCD copies -> padded count (scanned), dinv, per-node record
// combo[i] = {rofs (scan3), xb0..3 u8x4, xb4..7 u8x4, true_tot}.

__global__ __launch_bounds__(256) void scan1_kernel(const unsigned* __restrict__ packed,
                                                    unsigned* __restrict__ part, unsigned* __restrict__ bsums,
                                                    float* __restrict__ dinv, uint4* __restrict__ combo) {
  __shared__ unsigned s[256];
  int i = blockIdx.x * 256 + threadIdx.x;
  unsigned v = 0u;
  if (i < NNODES) {
    unsigned xb01 = 0, xb23 = 0, wsum = 0, tot = 0;
#pragma unroll
    for (int xc = 0; xc < 4; xc++) {
      unsigned r = packed[(size_t)xc * NNODES + i];
      xb01 |= tot << (xc * 8);
      tot += r >> 25;
      wsum += r & 0x1FFFFFFu;
    }
#pragma unroll
    for (int xc = 0; xc < 4; xc++) {
      unsigned r = packed[(size_t)(xc + 4) * NNODES + i];
      xb23 |= tot << (xc * 8);
      tot += r >> 25;
      wsum += r & 0x1FFFFFFu;
    }
    v = (tot + 3u) & ~3u;                                       // pad to x4
    dinv[i] = rsqrtf((float)wsum * (1.0f / 524288.0f) + 1.0f);
    combo[i] = make_uint4(0u, xb01, xb23, tot);
  }
  s[threadIdx.x] = v;
  __syncthreads();
  for (int off = 1; off < 256; off <<= 1) {
    unsigned t = (threadIdx.x >= off) ? s[threadIdx.x - off] : 0u;
    __syncthreads();
    s[threadIdx.x] += t;
    __syncthreads();
  }
  if (i < NNODES) part[i] = s[threadIdx.x] - v;
  if (threadIdx.x == 255) bsums[blockIdx.x] = s[255];
}

__global__ void scan2_kernel(unsigned* __restrict__ bsums, unsigned* __restrict__ row_ofs, int nb) {
  __shared__ unsigned s[512];
  unsigned v = ((int)threadIdx.x < nb) ? bsums[threadIdx.x] : 0u;
  s[threadIdx.x] = v;
  __syncthreads();
  for (int off = 1; off < 512; off <<= 1) {
    unsigned t = (threadIdx.x >= off) ? s[threadIdx.x - off] : 0u;
    __syncthreads();
    s[threadIdx.x] += t;
    __syncthreads();
  }
  if ((int)threadIdx.x < nb) bsums[threadIdx.x] = s[threadIdx.x] - v;
  if (threadIdx.x == 511) row_ofs[NNODES] = s[511];
}

__global__ __launch_bounds__(256) void scan3_kernel(unsigned* __restrict__ row_ofs,
                                                    const unsigned* __restrict__ bsums,
                                                    uint4* __restrict__ combo) {
  int i = blockIdx.x * 256 + threadIdx.x;
  if (i < NNODES) {
    unsigned v = row_ofs[i] + bsums[blockIdx.x];
    row_ofs[i] = v;
    reinterpret_cast<unsigned*>(&combo[i])[0] = v;   // combo[i].x = rofs
  }
}

// ============================ scatter + row-pad (fused grid) ============================

__global__ __launch_bounds__(256) void scatter_kernel(const int* __restrict__ ei, const float* __restrict__ ew,
                                                      const float* __restrict__ dinv,
                                                      const unsigned short* __restrict__ rank,
                                                      const uint4* __restrict__ combo,
                                                      uint2* __restrict__ edges) {
  const int b = blockIdx.x;
  if (b < EB) {
    int e = b * 256 + threadIdx.x;
    if (e >= NEDGES) return;
    int s = ei[e];
    int d = ei[NEDGES + e];
    unsigned r = rank[e];
    uint4 c = combo[d];
    unsigned xc = r >> 8;
    u64 xbp = (u64)c.y | ((u64)c.z << 32);
    unsigned xb = (unsigned)(xbp >> (xc * 8)) & 0xffu;
    unsigned pos = c.x + xb + (r & 0xffu);
    uint2 rec;
    rec.x = (unsigned)s;
    rec.y = __float_as_uint(ew[e] * dinv[s] * dinv[d]);
    edges[pos] = rec;
  } else {
    int i = (b - EB) * 256 + threadIdx.x;
    if (i >= NNODES) return;
    uint4 c = combo[i];
    unsigned p = c.x + c.w;
    unsigned end = c.x + ((c.w + 3u) & ~3u);
    for (; p < end; ++p) edges[p] = make_uint2(0u, 0u);
  }
}

// ============================ sharded aggregation: t = S · fsh ============================
// NSH column-shards of 16 cols (8 uint words, 32B) per node; shard region = N*32B = 3.2MB ->
// L2-resident on the XCD that owns it (shard = blockIdx & (NSH-1); consecutive blockIdx
// round-robin XCDs). Wave = one node: 8 lanes/edge-slot x 8 slots, 16 edges per iteration,
// shfl_xor tree folds slots, 8 lanes write the 32B t-span. Edge records + t stores are
// nontemporal so the resident shard isn't evicted. Masked tail (src,w -> 0) for idx >= re.

template <int NSH>
__global__ __launch_bounds__(256) void aggs_kernel(const unsigned* __restrict__ fsh,
                                                   const unsigned* __restrict__ row_ofs,
                                                   const uint2* __restrict__ edges,
                                                   const float* __restrict__ dinv,
                                                   unsigned* __restrict__ tb) {
  const int bid = blockIdx.x;
  const int shard = bid & (NSH - 1);
  int node = (bid / NSH) * 4 + (threadIdx.x >> 6);
  node = __builtin_amdgcn_readfirstlane(node);
  const int lane = threadIdx.x & 63;
  const int esub = lane >> 3;
  const int c = lane & 7;
  const unsigned* base = fsh + (size_t)shard * ((size_t)NNODES * 8);
  const unsigned ro = row_ofs[node], re = row_ofs[node + 1];
  float acc0 = 0.f, acc1 = 0.f;
  for (unsigned e = ro; e < re; e += 16) {
    unsigned i0 = e + esub, i1 = e + 8 + esub;
    u64 q0 = __builtin_nontemporal_load(reinterpret_cast<const u64*>(edges) + i0);
    u64 q1 = __builtin_nontemporal_load(reinterpret_cast<const u64*>(edges) + i1);
    unsigned s0 = (i0 < re) ? (unsigned)q0 : 0u;
    unsigned s1 = (i1 < re) ? (unsigned)q1 : 0u;
    float w0 = (i0 < re) ? __uint_as_float((unsigned)(q0 >> 32)) : 0.f;
    float w1 = (i1 < re) ? __uint_as_float((unsigned)(q1 >> 32)) : 0.f;
    half2_t v0 = __builtin_bit_cast(half2_t, base[s0 * 8 + c]);
    half2_t v1 = __builtin_bit_cast(half2_t, base[s1 * 8 + c]);
    acc0 = fmaf((float)v0.x, w0, acc0); acc1 = fmaf((float)v0.y, w0, acc1);
    acc0 = fmaf((float)v1.x, w1, acc0); acc1 = fmaf((float)v1.y, w1, acc1);
  }
#pragma unroll
  for (int m = 8; m < 64; m <<= 1) {
    acc0 += __shfl_xor(acc0, m);
    acc1 += __shfl_xor(acc1, m);
  }
  if (lane < 8) {
    const float di = dinv[node];
    const float ws = di * di;
    half2_t sv = __builtin_bit_cast(half2_t, base[(unsigned)node * 8 + lane]);
    acc0 = fmaf((float)sv.x, ws, acc0);
    acc1 = fmaf((float)sv.y, ws, acc1);
    __builtin_nontemporal_store(pack_bf16x2(acc0, acc1),
                                &tb[(size_t)node * (NSH * 8) + shard * 8 + lane]);
  }
}

// ============================ GEMM: W-stationary in VGPRs, persistent blocks ============================

#define GB 521   // ceil(1563/3)

template <int K>
__global__ __launch_bounds__(256) void gemm_kernel(const unsigned short* __restrict__ A,
                                                   const unsigned short* __restrict__ Wt,
                                                   const float* __restrict__ bias,
                                                   unsigned short* __restrict__ out,
                                                   float* __restrict__ stats) {
  constexpr int KP = K + 8;
  __shared__ __align__(16) unsigned short sA[64 * KP];
  __shared__ float sS[128], sQ[128];
  const int tid = threadIdx.x;
  if (tid < 128) { sS[tid] = 0.f; sQ[tid] = 0.f; }
  const int wid = tid >> 6;
  const int lane = tid & 63;
  const int wrow = wid * 16;
  const int fr = lane & 15;
  const int fk = (lane >> 4) * 8;

  bf16x8 wfrag[8][K / 32];
#pragma unroll
  for (int cf = 0; cf < 8; cf++)
#pragma unroll
    for (int ks = 0; ks < K / 32; ks++)
      wfrag[cf][ks] = *reinterpret_cast<const bf16x8*>(&Wt[(size_t)(cf * 16 + fr) * K + ks * 32 + fk]);
  float bv[8];
#pragma unroll
  for (int cf = 0; cf < 8; cf++) bv[cf] = bias[cf * 16 + fr];

  constexpr int CPR = K / 8;
  const uint4* Ag = (const uint4*)A;
  const int orow = (lane >> 4) * 4;

  for (int pan = blockIdx.x; pan * 64 < NNODES; pan += GB) {
    const int row0 = pan * 64;
    __syncthreads();
#pragma unroll
    for (int i = tid; i < 64 * CPR; i += 256) {
      int row = i / CPR, ch = i % CPR;
      int grow = row0 + row;
      uint4 v = make_uint4(0u, 0u, 0u, 0u);
      if (grow < NNODES) v = Ag[(size_t)grow * CPR + ch];
      *reinterpret_cast<uint4*>(&sA[row * KP + ch * 8]) = v;
    }
    __syncthreads();

    f32x4 acc[8];
#pragma unroll
    for (int cf = 0; cf < 8; cf++) acc[cf] = (f32x4){0.f, 0.f, 0.f, 0.f};
    bf16x8 afrag[K / 32];
#pragma unroll
    for (int ks = 0; ks < K / 32; ks++)
      afrag[ks] = *reinterpret_cast<const bf16x8*>(&sA[(wrow + fr) * KP + ks * 32 + fk]);
#pragma unroll
    for (int cf = 0; cf < 8; cf++)
#pragma unroll
      for (int ks = 0; ks < K / 32; ks++)
        acc[cf] = __builtin_amdgcn_mfma_f32_16x16x32_bf16(afrag[ks], wfrag[cf][ks], acc[cf], 0, 0, 0);

#pragma unroll
    for (int cf = 0; cf < 8; cf++) {
      const int col = cf * 16 + fr;
      float s = 0.f, q = 0.f;
#pragma unroll
      for (int j = 0; j < 4; j++) {
        int grow = row0 + wrow + orow + j;
        float val = 0.f;
        if (grow < NNODES) {
          unsigned short o = bf16r(acc[cf][j] + bv[cf]);
          out[(size_t)grow * HID + col] = o;
          val = __uint_as_float((unsigned)o << 16);
        }
        s += val; q += val * val;
      }
      s += __shfl_xor(s, 16); s += __shfl_xor(s, 32);
      q += __shfl_xor(q, 16); q += __shfl_xor(q, 32);
      if (lane < 16) { atomicAdd(&sS[col], s); atomicAdd(&sQ[col], q); }
    }
  }
  __syncthreads();
  if (tid < 128) {
    atomicAdd(&stats[tid],       sS[tid]);
    atomicAdd(&stats[128 + tid], sQ[tid]);
  }
}

// ============================ BN apply: fh = relu(bn(h)) fp16, SHARDED layout ============================
// 8 shards x 16 cols; shard s, node n occupies words [s*N*8 + n*8, +8).

__global__ __launch_bounds__(256) void bnapply_kernel(const uint4* __restrict__ hb,
                                                      const float* __restrict__ stats,
                                                      const float* __restrict__ gamma,
                                                      const float* __restrict__ beta,
                                                      uint4* __restrict__ fsh) {
  __shared__ float sc[128], sh[128];
  if (threadIdx.x < 128) {
    int c = threadIdx.x;
    float mu  = stats[c] * (1.0f / NNODES);
    float var = fmaf(-mu, mu, stats[128 + c] * (1.0f / NNODES));
    float scale = gamma[c] * rsqrtf(var + 1e-5f);
    sc[c] = scale;
    sh[c] = fmaf(-mu, scale, beta[c]);
  }
  __syncthreads();
  int i = blockIdx.x * 256 + threadIdx.x;   // grid exact: N*16/256
  uint4 v = hb[i];
  int node = i >> 4, j = i & 15;
  int cb = j * 8;
  float r0 = fmaxf(fmaf(bf16lo(v.x), sc[cb + 0], sh[cb + 0]), 0.f);
  float r1 = fmaxf(fmaf(bf16hi(v.x), sc[cb + 1], sh[cb + 1]), 0.f);
  float r2 = fmaxf(fmaf(bf16lo(v.y), sc[cb + 2], sh[cb + 2]), 0.f);
  float r3 = fmaxf(fmaf(bf16hi(v.y), sc[cb + 3], sh[cb + 3]), 0.f);
  float r4 = fmaxf(fmaf(bf16lo(v.z), sc[cb + 4], sh[cb + 4]), 0.f);
  float r5 = fmaxf(fmaf(bf16hi(v.z), sc[cb + 5], sh[cb + 5]), 0.f);
  float r6 = fmaxf(fmaf(bf16lo(v.w), sc[cb + 6], sh[cb + 6]), 0.f);
  float r7 = fmaxf(fmaf(bf16hi(v.w), sc[cb + 7], sh[cb + 7]), 0.f);
  // shard s = j>>1; uint4 slot (j&1) within the node's 8-word shard span
  fsh[(size_t)(j >> 1) * (NNODES * 2) + node * 2 + (j & 1)] =
      make_uint4(f16x2(r0, r1), f16x2(r2, r3), f16x2(r4, r5), f16x2(r6, r7));
}

// ============================ final BN (no ReLU) -> fp32 out ============================

__global__ __launch_bounds__(256) void normout_kernel(const unsigned* __restrict__ hb,
                                                      const float* __restrict__ stats,
                                                      const float* __restrict__ gamma,
                                                      const float* __restrict__ beta,
                                                      float2* __restrict__ out) {
  __shared__ float sc[128], sh[128];
  if (threadIdx.x < 128) {
    int c = threadIdx.x;
    float mu  = stats[c] * (1.0f / NNODES);
    float var = fmaf(-mu, mu, stats[128 + c] * (1.0f / NNODES));
    float scale = gamma[c] * rsqrtf(var + 1e-5f);
    sc[c] = scale;
    sh[c] = fmaf(-mu, scale, beta[c]);
  }
  __syncthreads();
  int i = blockIdx.x * 256 + threadIdx.x;   // grid exact: N*64/256
  unsigned u = hb[i];
  int c = (i & 63) * 2;
  out[i] = make_float2(fmaf(bf16lo(u), sc[c],     sh[c]),
                       fmaf(bf16hi(u), sc[c + 1], sh[c + 1]));
}

// ============================ launch ============================

extern "C" void kernel_launch(void* const* d_in, const int* in_sizes, int n_in,
                              void* d_out, int out_size, void* d_ws, size_t ws_size,
                              hipStream_t stream) {
  const float* x     = (const float*)d_in[0];
  const int*   ei    = (const int*)d_in[1];
  const float* ew    = (const float*)d_in[2];
  const float* W_in  = (const float*)d_in[3];
  const float* b_in  = (const float*)d_in[4];
  const float* W_mid = (const float*)d_in[5];
  const float* b_mid = (const float*)d_in[6];
  const float* W_out = (const float*)d_in[7];
  const float* b_out = (const float*)d_in[8];
  const float* gamma = (const float*)d_in[9];
  const float* beta  = (const float*)d_in[10];

  char* p = (char*)d_ws;
  auto alloc = [&](size_t bytes) -> char* {
    char* r = p;
    p += (bytes + 255) & ~(size_t)255;
    return r;
  };
  const size_t EPAD = (size_t)NEDGES + 3 * (size_t)NNODES + 32;
  unsigned* packed  = (unsigned*)alloc(8 * (size_t)NNODES * 4);  // [xcd][node], u32 packed
  float*    stats   = (float*)alloc(5 * 256 * 4);
  size_t zbytes = (size_t)(p - (char*)d_ws);          // only packed + stats zeroed
  uint2*    edges   = (uint2*)alloc(EPAD * 8);                   // pads written by scatter grid
  float*    dinv    = (float*)alloc((size_t)NNODES * 4);
  unsigned* row_ofs = (unsigned*)alloc((size_t)(NNODES + 1) * 4);
  uint4*    combo   = (uint4*)alloc((size_t)NNODES * 16);        // {rofs, xb0-3, xb4-7, tot}
  unsigned* bsums   = (unsigned*)alloc(512 * 4);
  unsigned short* rank = (unsigned short*)alloc((size_t)NEDGES * 2);
  unsigned* xsh     = (unsigned*)alloc((size_t)NNODES * INDIM * 2);  // 4-sharded fp16 x
  unsigned short* h = (unsigned short*)alloc((size_t)NNODES * HID * 2);
  unsigned short* t = (unsigned short*)alloc((size_t)NNODES * HID * 2);
  unsigned short* wt = (unsigned short*)alloc((size_t)WTOT * 2);
  unsigned* fsh     = (unsigned*)d_out;               // 8-sharded fp16 f(h) in d_out (25.6 of 51.2 MB)

  hipMemsetAsync(d_ws, 0, zbytes, stream);

  prep_kernel<<<EB + XB + WB, 256, 0, stream>>>(x, (uint2*)xsh, W_in, W_mid, W_out, wt, ei, ew, packed, rank);
  scan1_kernel<<<NB, 256, 0, stream>>>(packed, row_ofs, bsums, dinv, combo);
  scan2_kernel<<<1, 512, 0, stream>>>(bsums, row_ofs, NB);
  scan3_kernel<<<NB, 256, 0, stream>>>(row_ofs, bsums, combo);
  scatter_kernel<<<EB + NB, 256, 0, stream>>>(ei, ew, dinv, rank, combo, edges);

  // layer 0: t = S·x (4 shards); h = t @ W_in + b_in (stats[0] fused)
  aggs_kernel<4><<<(NNODES / 4) * 4, 256, 0, stream>>>(xsh, row_ofs, edges, dinv, (unsigned*)t);
  gemm_kernel<INDIM><<<GB, 256, 0, stream>>>((const unsigned short*)t, wt, b_in, h, stats);

  // layers 1..4
  for (int l = 1; l <= 4; l++) {
    bnapply_kernel<<<(NNODES * 16) / 256, 256, 0, stream>>>((const uint4*)h, stats + (size_t)(l - 1) * 256,
                                                            gamma + (size_t)(l - 1) * HID,
                                                            beta + (size_t)(l - 1) * HID, (uint4*)fsh);
    aggs_kernel<8><<<(NNODES / 4) * 8, 256, 0, stream>>>(fsh, row_ofs, edges, dinv, (unsigned*)t);
    const float* b = (l <= 3) ? (b_mid + (size_t)(l - 1) * HID) : b_out;
    const unsigned short* wl = wt + HID * INDIM + (size_t)(l - 1) * HID * HID;
    gemm_kernel<HID><<<GB, 256, 0, stream>>>((const unsigned short*)t, wl, b, h, stats + (size_t)l * 256);
  }

  // final BN (no ReLU) on h4 -> d_out (fp32); fsh region dead by now.
  normout_kernel<<<(NNODES * 64) / 256, 256, 0, stream>>>((const unsigned*)h, stats + 4 * 256,
                                                          gamma + 4 * HID, beta + 4 * HID, (float2*)d_out);
}

// Round 11
// 681.617 us; speedup vs baseline: 2.2836x; 2.2836x over previous
//
#include <hip/hip_runtime.h>

#define NNODES 100000
#define NEDGES 1600000
#define HID    128
#define INDIM  64

typedef __attribute__((ext_vector_type(8))) short bf16x8;
typedef __attribute__((ext_vector_type(4))) float f32x4;
typedef __attribute__((ext_vector_type(2))) _Float16 half2_t;
typedef unsigned long long u64;

__device__ __forceinline__ unsigned pack_bf16x2(float a, float b) {
  unsigned ua = __float_as_uint(a), ub = __float_as_uint(b);
  ua = (ua + 0x7fffu + ((ua >> 16) & 1u)) >> 16;
  ub = (ub + 0x7fffu + ((ub >> 16) & 1u)) >> 16;
  return ua | (ub << 16);
}
__device__ __forceinline__ unsigned short bf16r(float x) {
  unsigned u = __float_as_uint(x);
  u = (u + 0x7fffu + ((u >> 16) & 1u)) >> 16;
  return (unsigned short)u;
}
__device__ __forceinline__ float bf16lo(unsigned u) { return __uint_as_float(u << 16); }
__device__ __forceinline__ float bf16hi(unsigned u) { return __uint_as_float(u & 0xffff0000u); }
__device__ __forceinline__ unsigned f16x2(float a, float b) {
  half2_t h; h.x = (_Float16)a; h.y = (_Float16)b;
  return __builtin_bit_cast(unsigned, h);
}

// ============================ fused prep: hist | xprep | wtprep ============================
// Section A (blocks [0,EB)): per-XCD-privatized u32 packed histogram — count [31:25] (7b),
//   wdeg Q6.19 [24:0]. Per-XCD copy = 400KB -> L2-resident, workgroup-scope atomics execute
//   in the local L2 (~23 atomic-ops/ns chip-wide = TCC atomic issue floor, measured r8/r9).
//   rank[e] (u16) = xcc<<8 | within-copy rank.
// Section B: x -> fp16.  Section C: W transpose -> bf16, layout [c][K].

#define XB ((NNODES * INDIM / 4) / 256)                 // 6250
#define WTOT (HID * INDIM + 4 * HID * HID)              // 73728
#define WB ((WTOT + 255) / 256)                         // 288
#define EB ((NEDGES + 255) / 256)                       // 6250
#define NB ((NNODES + 255) / 256)                       // 391

__global__ __launch_bounds__(256) void prep_kernel(const float* __restrict__ x, uint2* __restrict__ xh,
                                                   const float* __restrict__ W_in, const float* __restrict__ W_mid,
                                                   const float* __restrict__ W_out, unsigned short* __restrict__ wt,
                                                   const int* __restrict__ ei, const float* __restrict__ ew,
                                                   unsigned* __restrict__ packed,
                                                   unsigned short* __restrict__ rank) {
  const int b = blockIdx.x;
  if (b < EB) {
    int e = b * 256 + threadIdx.x;
    if (e < NEDGES) {
      unsigned xcc;
      asm volatile("s_getreg_b32 %0, hwreg(HW_REG_XCC_ID)" : "=s"(xcc));
      xcc &= 7u;
      int d = ei[NEDGES + e];
      unsigned inc = (1u << 25) | (unsigned)(ew[e] * 524288.0f + 0.5f);
      unsigned old = __hip_atomic_fetch_add(&packed[(size_t)xcc * NNODES + d], inc,
                                            __ATOMIC_RELAXED, __HIP_MEMORY_SCOPE_WORKGROUP);
      rank[e] = (unsigned short)((xcc << 8) | (old >> 25));
    }
  } else if (b < EB + XB) {
    int i = (b - EB) * 256 + threadIdx.x;
    float4 v = reinterpret_cast<const float4*>(x)[i];
    xh[i] = make_uint2(f16x2(v.x, v.y), f16x2(v.z, v.w));
  } else {
    int idx = (b - EB - XB) * 256 + threadIdx.x;
    if (idx < WTOT) {
      float v;
      if (idx < HID * INDIM) {
        int c = idx / INDIM, k = idx % INDIM;
        v = W_in[(size_t)k * HID + c];
      } else {
        int r = idx - HID * INDIM;
        int l = r / (HID * HID), j = r % (HID * HID);
        int c = j / HID, k = j % HID;
        const float* W = (l < 3) ? (W_mid + (size_t)l * HID * HID) : W_out;
        v = W[(size_t)k * HID + c];
      }
      wt[idx] = bf16r(v);
    }
  }
}

// ============================ scans ============================
// scan1: reduce 8 XCD copies -> padded count (scanned), dinv, per-node record
// combo[i] = {rofs (scan3), xb0..3 u8x4, xb4..7 u8x4, true_tot}.

__global__ __launch_bounds__(256) void scan1_kernel(const unsigned* __restrict__ packed,
                                                    unsigned* __restrict__ part, unsigned* __restrict__ bsums,
                                                    float* __restrict__ dinv, uint4* __restrict__ combo) {
  __shared__ unsigned s[256];
  int i = blockIdx.x * 256 + threadIdx.x;
  unsigned v = 0u;
  if (i < NNODES) {
    unsigned xb01 = 0, xb23 = 0, wsum = 0, tot = 0;
#pragma unroll
    for (int xc = 0; xc < 4; xc++) {
      unsigned r = packed[(size_t)xc * NNODES + i];
      xb01 |= tot << (xc * 8);
      tot += r >> 25;
      wsum += r & 0x1FFFFFFu;
    }
#pragma unroll
    for (int xc = 0; xc < 4; xc++) {
      unsigned r = packed[(size_t)(xc + 4) * NNODES + i];
      xb23 |= tot << (xc * 8);
      tot += r >> 25;
      wsum += r & 0x1FFFFFFu;
    }
    v = (tot + 3u) & ~3u;                                       // pad to x4
    dinv[i] = rsqrtf((float)wsum * (1.0f / 524288.0f) + 1.0f);
    combo[i] = make_uint4(0u, xb01, xb23, tot);
  }
  s[threadIdx.x] = v;
  __syncthreads();
  for (int off = 1; off < 256; off <<= 1) {
    unsigned t = (threadIdx.x >= off) ? s[threadIdx.x - off] : 0u;
    __syncthreads();
    s[threadIdx.x] += t;
    __syncthreads();
  }
  if (i < NNODES) part[i] = s[threadIdx.x] - v;
  if (threadIdx.x == 255) bsums[blockIdx.x] = s[255];
}

__global__ void scan2_kernel(unsigned* __restrict__ bsums, unsigned* __restrict__ row_ofs, int nb) {
  __shared__ unsigned s[512];
  unsigned v = ((int)threadIdx.x < nb) ? bsums[threadIdx.x] : 0u;
  s[threadIdx.x] = v;
  __syncthreads();
  for (int off = 1; off < 512; off <<= 1) {
    unsigned t = (threadIdx.x >= off) ? s[threadIdx.x - off] : 0u;
    __syncthreads();
    s[threadIdx.x] += t;
    __syncthreads();
  }
  if ((int)threadIdx.x < nb) bsums[threadIdx.x] = s[threadIdx.x] - v;
  if (threadIdx.x == 511) row_ofs[NNODES] = s[511];
}

__global__ __launch_bounds__(256) void scan3_kernel(unsigned* __restrict__ row_ofs,
                                                    const unsigned* __restrict__ bsums,
                                                    uint4* __restrict__ combo) {
  int i = blockIdx.x * 256 + threadIdx.x;
  if (i < NNODES) {
    unsigned v = row_ofs[i] + bsums[blockIdx.x];
    row_ofs[i] = v;
    reinterpret_cast<unsigned*>(&combo[i])[0] = v;   // combo[i].x = rofs
  }
}

// ============================ scatter + row-pad (fused grid) ============================
// Blocks [0,EB): edges[pos] = {src, float_bits(norm)}; pos = rofs + xb[xcc] + local_rank.
// Blocks [EB,EB+NB): zero the <=3 pad slots per row (replaces 115MB memset of edges).

__global__ __launch_bounds__(256) void scatter_kernel(const int* __restrict__ ei, const float* __restrict__ ew,
                                                      const float* __restrict__ dinv,
                                                      const unsigned short* __restrict__ rank,
                                                      const uint4* __restrict__ combo,
                                                      uint2* __restrict__ edges) {
  const int b = blockIdx.x;
  if (b < EB) {
    int e = b * 256 + threadIdx.x;
    if (e >= NEDGES) return;
    int s = ei[e];
    int d = ei[NEDGES + e];
    unsigned r = rank[e];
    uint4 c = combo[d];
    unsigned xc = r >> 8;
    u64 xbp = (u64)c.y | ((u64)c.z << 32);
    unsigned xb = (unsigned)(xbp >> (xc * 8)) & 0xffu;
    unsigned pos = c.x + xb + (r & 0xffu);
    uint2 rec;
    rec.x = (unsigned)s;
    rec.y = __float_as_uint(ew[e] * dinv[s] * dinv[d]);
    edges[pos] = rec;
  } else {
    int i = (b - EB) * 256 + threadIdx.x;
    if (i >= NNODES) return;
    uint4 c = combo[i];
    unsigned p = c.x + c.w;
    unsigned end = c.x + ((c.w + 3u) & ~3u);
    for (; p < end; ++p) edges[p] = make_uint2(0u, 0u);
  }
}

// ============================ aggregation: t = S · fh (fp16 rows, fp32 accum) ============================
// LANES=64: one wave per node (scalar edge stream); LANES=32: two nodes per wave (layer 0).
// Edge lists padded to x4 with zero records; 16-wide main loop + 8/4-wide tails (deep MLP).

template <int LANES>
__global__ __launch_bounds__(256) void agg_kernel(const unsigned* __restrict__ hh,
                                                  const unsigned* __restrict__ row_ofs,
                                                  const uint2* __restrict__ edges,
                                                  const float* __restrict__ dinv,
                                                  unsigned* __restrict__ tb) {
  int gid = blockIdx.x * 256 + threadIdx.x;
  int node = gid / LANES;
  const int lane = gid % LANES;
  if (LANES == 64) node = __builtin_amdgcn_readfirstlane(node);
  const unsigned ro = row_ofs[node], re = row_ofs[node + 1];
  const float di = dinv[node];
  const float wself = di * di;
  half2_t sv = __builtin_bit_cast(half2_t, hh[(unsigned)node * LANES + lane]);
  float acc0 = (float)sv.x * wself;
  float acc1 = (float)sv.y * wself;
  unsigned e = ro;
  for (; e + 16 <= re; e += 16) {
    uint2 q[16];
#pragma unroll
    for (int j = 0; j < 16; j++) q[j] = edges[e + j];
    unsigned vv[16];
#pragma unroll
    for (int j = 0; j < 16; j++) vv[j] = hh[q[j].x * LANES + lane];
#pragma unroll
    for (int j = 0; j < 16; j++) {
      const float w = __uint_as_float(q[j].y);
      half2_t v = __builtin_bit_cast(half2_t, vv[j]);
      acc0 = fmaf((float)v.x, w, acc0);
      acc1 = fmaf((float)v.y, w, acc1);
    }
  }
  for (; e + 8 <= re; e += 8) {
    uint2 q[8];
#pragma unroll
    for (int j = 0; j < 8; j++) q[j] = edges[e + j];
    unsigned vv[8];
#pragma unroll
    for (int j = 0; j < 8; j++) vv[j] = hh[q[j].x * LANES + lane];
#pragma unroll
    for (int j = 0; j < 8; j++) {
      const float w = __uint_as_float(q[j].y);
      half2_t v = __builtin_bit_cast(half2_t, vv[j]);
      acc0 = fmaf((float)v.x, w, acc0);
      acc1 = fmaf((float)v.y, w, acc1);
    }
  }
  if (e < re) {
    uint2 q[4];
#pragma unroll
    for (int j = 0; j < 4; j++) q[j] = edges[e + j];
    unsigned vv[4];
#pragma unroll
    for (int j = 0; j < 4; j++) vv[j] = hh[q[j].x * LANES + lane];
#pragma unroll
    for (int j = 0; j < 4; j++) {
      const float w = __uint_as_float(q[j].y);
      half2_t v = __builtin_bit_cast(half2_t, vv[j]);
      acc0 = fmaf((float)v.x, w, acc0);
      acc1 = fmaf((float)v.y, w, acc1);
    }
  }
  tb[(unsigned)node * LANES + lane] = pack_bf16x2(acc0, acc1);
}

// ============================ GEMM: W-stationary in VGPRs, persistent blocks ============================

#define GB 521   // ceil(1563/3)

template <int K>
__global__ __launch_bounds__(256) void gemm_kernel(const unsigned short* __restrict__ A,
                                                   const unsigned short* __restrict__ Wt,
                                                   const float* __restrict__ bias,
                                                   unsigned short* __restrict__ out,
                                                   float* __restrict__ stats) {
  constexpr int KP = K + 8;
  __shared__ __align__(16) unsigned short sA[64 * KP];
  __shared__ float sS[128], sQ[128];
  const int tid = threadIdx.x;
  if (tid < 128) { sS[tid] = 0.f; sQ[tid] = 0.f; }
  const int wid = tid >> 6;
  const int lane = tid & 63;
  const int wrow = wid * 16;
  const int fr = lane & 15;
  const int fk = (lane >> 4) * 8;

  bf16x8 wfrag[8][K / 32];
#pragma unroll
  for (int cf = 0; cf < 8; cf++)
#pragma unroll
    for (int ks = 0; ks < K / 32; ks++)
      wfrag[cf][ks] = *reinterpret_cast<const bf16x8*>(&Wt[(size_t)(cf * 16 + fr) * K + ks * 32 + fk]);
  float bv[8];
#pragma unroll
  for (int cf = 0; cf < 8; cf++) bv[cf] = bias[cf * 16 + fr];

  constexpr int CPR = K / 8;
  const uint4* Ag = (const uint4*)A;
  const int orow = (lane >> 4) * 4;

  for (int pan = blockIdx.x; pan * 64 < NNODES; pan += GB) {
    const int row0 = pan * 64;
    __syncthreads();
#pragma unroll
    for (int i = tid; i < 64 * CPR; i += 256) {
      int row = i / CPR, ch = i % CPR;
      int grow = row0 + row;
      uint4 v = make_uint4(0u, 0u, 0u, 0u);
      if (grow < NNODES) v = Ag[(size_t)grow * CPR + ch];
      *reinterpret_cast<uint4*>(&sA[row * KP + ch * 8]) = v;
    }
    __syncthreads();

    f32x4 acc[8];
#pragma unroll
    for (int cf = 0; cf < 8; cf++) acc[cf] = (f32x4){0.f, 0.f, 0.f, 0.f};
    bf16x8 afrag[K / 32];
#pragma unroll
    for (int ks = 0; ks < K / 32; ks++)
      afrag[ks] = *reinterpret_cast<const bf16x8*>(&sA[(wrow + fr) * KP + ks * 32 + fk]);
#pragma unroll
    for (int cf = 0; cf < 8; cf++)
#pragma unroll
      for (int ks = 0; ks < K / 32; ks++)
        acc[cf] = __builtin_amdgcn_mfma_f32_16x16x32_bf16(afrag[ks], wfrag[cf][ks], acc[cf], 0, 0, 0);

#pragma unroll
    for (int cf = 0; cf < 8; cf++) {
      const int col = cf * 16 + fr;
      float s = 0.f, q = 0.f;
#pragma unroll
      for (int j = 0; j < 4; j++) {
        int grow = row0 + wrow + orow + j;
        float val = 0.f;
        if (grow < NNODES) {
          unsigned short o = bf16r(acc[cf][j] + bv[cf]);
          out[(size_t)grow * HID + col] = o;
          val = __uint_as_float((unsigned)o << 16);
        }
        s += val; q += val * val;
      }
      s += __shfl_xor(s, 16); s += __shfl_xor(s, 32);
      q += __shfl_xor(q, 16); q += __shfl_xor(q, 32);
      if (lane < 16) { atomicAdd(&sS[col], s); atomicAdd(&sQ[col], q); }
    }
  }
  __syncthreads();
  if (tid < 128) {
    atomicAdd(&stats[tid],       sS[tid]);
    atomicAdd(&stats[128 + tid], sQ[tid]);
  }
}

// ============================ BN apply (inline finalize): fh = relu(bn(h)) fp16 ============================

__global__ __launch_bounds__(256) void bnapply_kernel(const uint4* __restrict__ hb,
                                                      const float* __restrict__ stats,
                                                      const float* __restrict__ gamma,
                                                      const float* __restrict__ beta,
                                                      uint4* __restrict__ fh) {
  __shared__ float sc[128], sh[128];
  if (threadIdx.x < 128) {
    int c = threadIdx.x;
    float mu  = stats[c] * (1.0f / NNODES);
    float var = fmaf(-mu, mu, stats[128 + c] * (1.0f / NNODES));
    float scale = gamma[c] * rsqrtf(var + 1e-5f);
    sc[c] = scale;
    sh[c] = fmaf(-mu, scale, beta[c]);
  }
  __syncthreads();
  int i = blockIdx.x * 256 + threadIdx.x;   // grid exact: N*16/256
  uint4 v = hb[i];
  int cb = (i & 15) * 8;
  float r0 = fmaxf(fmaf(bf16lo(v.x), sc[cb + 0], sh[cb + 0]), 0.f);
  float r1 = fmaxf(fmaf(bf16hi(v.x), sc[cb + 1], sh[cb + 1]), 0.f);
  float r2 = fmaxf(fmaf(bf16lo(v.y), sc[cb + 2], sh[cb + 2]), 0.f);
  float r3 = fmaxf(fmaf(bf16hi(v.y), sc[cb + 3], sh[cb + 3]), 0.f);
  float r4 = fmaxf(fmaf(bf16lo(v.z), sc[cb + 4], sh[cb + 4]), 0.f);
  float r5 = fmaxf(fmaf(bf16hi(v.z), sc[cb + 5], sh[cb + 5]), 0.f);
  float r6 = fmaxf(fmaf(bf16lo(v.w), sc[cb + 6], sh[cb + 6]), 0.f);
  float r7 = fmaxf(fmaf(bf16hi(v.w), sc[cb + 7], sh[cb + 7]), 0.f);
  fh[i] = make_uint4(f16x2(r0, r1), f16x2(r2, r3), f16x2(r4, r5), f16x2(r6, r7));
}

// ============================ final BN (no ReLU) -> fp32 out ============================

__global__ __launch_bounds__(256) void normout_kernel(const unsigned* __restrict__ hb,
                                                      const float* __restrict__ stats,
                                                      const float* __restrict__ gamma,
                                                      const float* __restrict__ beta,
                                                      float2* __restrict__ out) {
  __shared__ float sc[128], sh[128];
  if (threadIdx.x < 128) {
    int c = threadIdx.x;
    float mu  = stats[c] * (1.0f / NNODES);
    float var = fmaf(-mu, mu, stats[128 + c] * (1.0f / NNODES));
    float scale = gamma[c] * rsqrtf(var + 1e-5f);
    sc[c] = scale;
    sh[c] = fmaf(-mu, scale, beta[c]);
  }
  __syncthreads();
  int i = blockIdx.x * 256 + threadIdx.x;   // grid exact: N*64/256
  unsigned u = hb[i];
  int c = (i & 63) * 2;
  out[i] = make_float2(fmaf(bf16lo(u), sc[c],     sh[c]),
                       fmaf(bf16hi(u), sc[c + 1], sh[c + 1]));
}

// ============================ launch ============================

extern "C" void kernel_launch(void* const* d_in, const int* in_sizes, int n_in,
                              void* d_out, int out_size, void* d_ws, size_t ws_size,
                              hipStream_t stream) {
  const float* x     = (const float*)d_in[0];
  const int*   ei    = (const int*)d_in[1];
  const float* ew    = (const float*)d_in[2];
  const float* W_in  = (const float*)d_in[3];
  const float* b_in  = (const float*)d_in[4];
  const float* W_mid = (const float*)d_in[5];
  const float* b_mid = (const float*)d_in[6];
  const float* W_out = (const float*)d_in[7];
  const float* b_out = (const float*)d_in[8];
  const float* gamma = (const float*)d_in[9];
  const float* beta  = (const float*)d_in[10];

  char* p = (char*)d_ws;
  auto alloc = [&](size_t bytes) -> char* {
    char* r = p;
    p += (bytes + 255) & ~(size_t)255;
    return r;
  };
  const size_t EPAD = (size_t)NEDGES + 3 * (size_t)NNODES + 32;
  unsigned* packed  = (unsigned*)alloc(8 * (size_t)NNODES * 4);  // [xcd][node], u32 packed
  float*    stats   = (float*)alloc(5 * 256 * 4);
  size_t zbytes = (size_t)(p - (char*)d_ws);          // only packed + stats zeroed
  uint2*    edges   = (uint2*)alloc(EPAD * 8);                   // pads written by scatter grid
  float*    dinv    = (float*)alloc((size_t)NNODES * 4);
  unsigned* row_ofs = (unsigned*)alloc((size_t)(NNODES + 1) * 4);
  uint4*    combo   = (uint4*)alloc((size_t)NNODES * 16);        // {rofs, xb0-3, xb4-7, tot}
  unsigned* bsums   = (unsigned*)alloc(512 * 4);
  unsigned short* rank = (unsigned short*)alloc((size_t)NEDGES * 2);
  unsigned* xh      = (unsigned*)alloc((size_t)NNODES * INDIM * 2);
  unsigned short* h = (unsigned short*)alloc((size_t)NNODES * HID * 2);
  unsigned short* t = (unsigned short*)alloc((size_t)NNODES * HID * 2);
  unsigned short* wt = (unsigned short*)alloc((size_t)WTOT * 2);
  uint4*    fh      = (uint4*)d_out;                  // fp16 f(h) scratch in d_out (25.6 of 51.2 MB)

  hipMemsetAsync(d_ws, 0, zbytes, stream);

  prep_kernel<<<EB + XB + WB, 256, 0, stream>>>(x, (uint2*)xh, W_in, W_mid, W_out, wt, ei, ew, packed, rank);
  scan1_kernel<<<NB, 256, 0, stream>>>(packed, row_ofs, bsums, dinv, combo);
  scan2_kernel<<<1, 512, 0, stream>>>(bsums, row_ofs, NB);
  scan3_kernel<<<NB, 256, 0, stream>>>(row_ofs, bsums, combo);
  scatter_kernel<<<EB + NB, 256, 0, stream>>>(ei, ew, dinv, rank, combo, edges);

  // layer 0: t = S·x ; h = t @ W_in + b_in (stats[0] fused)
  agg_kernel<32><<<(NNODES * 32) / 256, 256, 0, stream>>>(xh, row_ofs, edges, dinv, (unsigned*)t);
  gemm_kernel<INDIM><<<GB, 256, 0, stream>>>((const unsigned short*)t, wt, b_in, h, stats);

  // layers 1..4
  for (int l = 1; l <= 4; l++) {
    bnapply_kernel<<<(NNODES * 16) / 256, 256, 0, stream>>>((const uint4*)h, stats + (size_t)(l - 1) * 256,
                                                            gamma + (size_t)(l - 1) * HID,
                                                            beta + (size_t)(l - 1) * HID, fh);
    agg_kernel<64><<<(NNODES * 64) / 256, 256, 0, stream>>>((const unsigned*)fh, row_ofs, edges, dinv, (unsigned*)t);
    const float* b = (l <= 3) ? (b_mid + (size_t)(l - 1) * HID) : b_out;
    const unsigned short* wl = wt + HID * INDIM + (size_t)(l - 1) * HID * HID;
    gemm_kernel<HID><<<GB, 256, 0, stream>>>((const unsigned short*)t, wl, b, h, stats + (size_t)l * 256);
  }

  // final BN (no ReLU) on h4 -> d_out (fp32); fh region dead by now.
  normout_kernel<<<(NNODES * 64) / 256, 256, 0, stream>>>((const unsigned*)h, stats + 4 * 256,
                                                          gamma + 4 * HID, beta + 4 * HID, (float2*)d_out);
}

// Round 12
// 662.242 us; speedup vs baseline: 2.3504x; 1.0293x over previous
//
#include <hip/hip_runtime.h>

#define NNODES 100000
#define NEDGES 1600000
#define HID    128
#define INDIM  64

typedef __attribute__((ext_vector_type(8))) short bf16x8;
typedef __attribute__((ext_vector_type(4))) float f32x4;
typedef __attribute__((ext_vector_type(2))) _Float16 half2_t;
typedef unsigned long long u64;

__device__ __forceinline__ unsigned pack_bf16x2(float a, float b) {
  unsigned ua = __float_as_uint(a), ub = __float_as_uint(b);
  ua = (ua + 0x7fffu + ((ua >> 16) & 1u)) >> 16;
  ub = (ub + 0x7fffu + ((ub >> 16) & 1u)) >> 16;
  return ua | (ub << 16);
}
__device__ __forceinline__ unsigned short bf16r(float x) {
  unsigned u = __float_as_uint(x);
  u = (u + 0x7fffu + ((u >> 16) & 1u)) >> 16;
  return (unsigned short)u;
}
__device__ __forceinline__ float bf16lo(unsigned u) { return __uint_as_float(u << 16); }
__device__ __forceinline__ float bf16hi(unsigned u) { return __uint_as_float(u & 0xffff0000u); }
__device__ __forceinline__ unsigned f16x2(float a, float b) {
  half2_t h; h.x = (_Float16)a; h.y = (_Float16)b;
  return __builtin_bit_cast(unsigned, h);
}
// decode 4B edge record {src:17b | norm:fp16-sans-sign:15b}
__device__ __forceinline__ float rec_norm(unsigned rec) {
  return (float)__builtin_bit_cast(_Float16, (unsigned short)(rec & 0x7FFFu));
}

// ============================ fused prep: hist | xprep | wtprep ============================
// Section A (blocks [0,EB)): per-XCD-privatized u32 packed histogram — count [31:25] (7b),
//   wdeg Q6.19 [24:0]. Per-XCD copy = 400KB -> L2-resident, workgroup-scope atomics execute
//   in the local L2 (~23 atomic-ops/ns chip-wide = TCC atomic issue floor, measured r8/r9).
//   rank[e] (u16) = xcc<<8 | within-copy rank.
// Section B: x -> fp16.  Section C: W transpose -> bf16, layout [c][K].

#define XB ((NNODES * INDIM / 4) / 256)                 // 6250
#define WTOT (HID * INDIM + 4 * HID * HID)              // 73728
#define WB ((WTOT + 255) / 256)                         // 288
#define EB ((NEDGES + 255) / 256)                       // 6250
#define NB ((NNODES + 255) / 256)                       // 391

__global__ __launch_bounds__(256) void prep_kernel(const float* __restrict__ x, uint2* __restrict__ xh,
                                                   const float* __restrict__ W_in, const float* __restrict__ W_mid,
                                                   const float* __restrict__ W_out, unsigned short* __restrict__ wt,
                                                   const int* __restrict__ ei, const float* __restrict__ ew,
                                                   unsigned* __restrict__ packed,
                                                   unsigned short* __restrict__ rank) {
  const int b = blockIdx.x;
  if (b < EB) {
    int e = b * 256 + threadIdx.x;
    if (e < NEDGES) {
      unsigned xcc;
      asm volatile("s_getreg_b32 %0, hwreg(HW_REG_XCC_ID)" : "=s"(xcc));
      xcc &= 7u;
      int d = ei[NEDGES + e];
      unsigned inc = (1u << 25) | (unsigned)(ew[e] * 524288.0f + 0.5f);
      unsigned old = __hip_atomic_fetch_add(&packed[(size_t)xcc * NNODES + d], inc,
                                            __ATOMIC_RELAXED, __HIP_MEMORY_SCOPE_WORKGROUP);
      rank[e] = (unsigned short)((xcc << 8) | (old >> 25));
    }
  } else if (b < EB + XB) {
    int i = (b - EB) * 256 + threadIdx.x;
    float4 v = reinterpret_cast<const float4*>(x)[i];
    xh[i] = make_uint2(f16x2(v.x, v.y), f16x2(v.z, v.w));
  } else {
    int idx = (b - EB - XB) * 256 + threadIdx.x;
    if (idx < WTOT) {
      float v;
      if (idx < HID * INDIM) {
        int c = idx / INDIM, k = idx % INDIM;
        v = W_in[(size_t)k * HID + c];
      } else {
        int r = idx - HID * INDIM;
        int l = r / (HID * HID), j = r % (HID * HID);
        int c = j / HID, k = j % HID;
        const float* W = (l < 3) ? (W_mid + (size_t)l * HID * HID) : W_out;
        v = W[(size_t)k * HID + c];
      }
      wt[idx] = bf16r(v);
    }
  }
}

// ============================ scans ============================
// scan1: reduce 8 XCD copies -> padded count (scanned), dinv, per-node record
// combo[i] = {rofs (scan3), xb0..3 u8x4, xb4..7 u8x4, true_tot}.

__global__ __launch_bounds__(256) void scan1_kernel(const unsigned* __restrict__ packed,
                                                    unsigned* __restrict__ part, unsigned* __restrict__ bsums,
                                                    float* __restrict__ dinv, uint4* __restrict__ combo) {
  __shared__ unsigned s[256];
  int i = blockIdx.x * 256 + threadIdx.x;
  unsigned v = 0u;
  if (i < NNODES) {
    unsigned xb01 = 0, xb23 = 0, wsum = 0, tot = 0;
#pragma unroll
    for (int xc = 0; xc < 4; xc++) {
      unsigned r = packed[(size_t)xc * NNODES + i];
      xb01 |= tot << (xc * 8);
      tot += r >> 25;
      wsum += r & 0x1FFFFFFu;
    }
#pragma unroll
    for (int xc = 0; xc < 4; xc++) {
      unsigned r = packed[(size_t)(xc + 4) * NNODES + i];
      xb23 |= tot << (xc * 8);
      tot += r >> 25;
      wsum += r & 0x1FFFFFFu;
    }
    v = (tot + 3u) & ~3u;                                       // pad to x4
    dinv[i] = rsqrtf((float)wsum * (1.0f / 524288.0f) + 1.0f);
    combo[i] = make_uint4(0u, xb01, xb23, tot);
  }
  s[threadIdx.x] = v;
  __syncthreads();
  for (int off = 1; off < 256; off <<= 1) {
    unsigned t = (threadIdx.x >= off) ? s[threadIdx.x - off] : 0u;
    __syncthreads();
    s[threadIdx.x] += t;
    __syncthreads();
  }
  if (i < NNODES) part[i] = s[threadIdx.x] - v;
  if (threadIdx.x == 255) bsums[blockIdx.x] = s[255];
}

__global__ void scan2_kernel(unsigned* __restrict__ bsums, unsigned* __restrict__ row_ofs, int nb) {
  __shared__ unsigned s[512];
  unsigned v = ((int)threadIdx.x < nb) ? bsums[threadIdx.x] : 0u;
  s[threadIdx.x] = v;
  __syncthreads();
  for (int off = 1; off < 512; off <<= 1) {
    unsigned t = (threadIdx.x >= off) ? s[threadIdx.x - off] : 0u;
    __syncthreads();
    s[threadIdx.x] += t;
    __syncthreads();
  }
  if ((int)threadIdx.x < nb) bsums[threadIdx.x] = s[threadIdx.x] - v;
  if (threadIdx.x == 511) row_ofs[NNODES] = s[511];
}

__global__ __launch_bounds__(256) void scan3_kernel(unsigned* __restrict__ row_ofs,
                                                    const unsigned* __restrict__ bsums,
                                                    uint4* __restrict__ combo) {
  int i = blockIdx.x * 256 + threadIdx.x;
  if (i < NNODES) {
    unsigned v = row_ofs[i] + bsums[blockIdx.x];
    row_ofs[i] = v;
    reinterpret_cast<unsigned*>(&combo[i])[0] = v;   // combo[i].x = rofs
  }
}

// ============================ scatter + row-pad (fused grid) ============================
// Blocks [0,EB): edges[pos] = {src:17b | norm fp16[14:0]}; pos = rofs + xb[xcc] + local_rank.
// Blocks [EB,EB+NB): zero the <=3 pad slots per row.

__global__ __launch_bounds__(256) void scatter_kernel(const int* __restrict__ ei, const float* __restrict__ ew,
                                                      const float* __restrict__ dinv,
                                                      const unsigned short* __restrict__ rank,
                                                      const uint4* __restrict__ combo,
                                                      unsigned* __restrict__ edges) {
  const int b = blockIdx.x;
  if (b < EB) {
    int e = b * 256 + threadIdx.x;
    if (e >= NEDGES) return;
    int s = ei[e];
    int d = ei[NEDGES + e];
    unsigned r = rank[e];
    uint4 c = combo[d];
    unsigned xc = r >> 8;
    u64 xbp = (u64)c.y | ((u64)c.z << 32);
    unsigned xb = (unsigned)(xbp >> (xc * 8)) & 0xffu;
    unsigned pos = c.x + xb + (r & 0xffu);
    float norm = ew[e] * dinv[s] * dinv[d];
    unsigned short h16 = __builtin_bit_cast(unsigned short, (_Float16)norm);
    edges[pos] = ((unsigned)s << 15) | (h16 & 0x7FFFu);
  } else {
    int i = (b - EB) * 256 + threadIdx.x;
    if (i >= NNODES) return;
    uint4 c = combo[i];
    unsigned p = c.x + c.w;
    unsigned end = c.x + ((c.w + 3u) & ~3u);
    for (; p < end; ++p) edges[p] = 0u;
  }
}

// ============================ aggregation: t = S · fh (fp16 rows, fp32 accum) ============================
// LANES=64: one wave per node (scalar edge stream); LANES=32: two nodes per wave (layer 0).
// 4B edge records, rows padded to x4 with zero records (src=0, w=+0) -> branchless.
// All row offsets are x4 -> uint4 edge loads are aligned. 16-wide main loop + 8/4 tails.

template <int LANES>
__global__ __launch_bounds__(256) void agg_kernel(const unsigned* __restrict__ hh,
                                                  const unsigned* __restrict__ row_ofs,
                                                  const unsigned* __restrict__ edges,
                                                  const float* __restrict__ dinv,
                                                  unsigned* __restrict__ tb) {
  int gid = blockIdx.x * 256 + threadIdx.x;
  int node = gid / LANES;
  const int lane = gid % LANES;
  if (LANES == 64) node = __builtin_amdgcn_readfirstlane(node);
  const unsigned ro = row_ofs[node], re = row_ofs[node + 1];
  const float di = dinv[node];
  const float wself = di * di;
  half2_t sv = __builtin_bit_cast(half2_t, hh[(unsigned)node * LANES + lane]);
  float acc0 = (float)sv.x * wself;
  float acc1 = (float)sv.y * wself;
  unsigned e = ro;
  for (; e + 16 <= re; e += 16) {
    uint4 r0 = *reinterpret_cast<const uint4*>(&edges[e]);
    uint4 r1 = *reinterpret_cast<const uint4*>(&edges[e + 4]);
    uint4 r2 = *reinterpret_cast<const uint4*>(&edges[e + 8]);
    uint4 r3 = *reinterpret_cast<const uint4*>(&edges[e + 12]);
    unsigned q[16] = {r0.x, r0.y, r0.z, r0.w, r1.x, r1.y, r1.z, r1.w,
                      r2.x, r2.y, r2.z, r2.w, r3.x, r3.y, r3.z, r3.w};
    unsigned vv[16];
#pragma unroll
    for (int j = 0; j < 16; j++) vv[j] = hh[(q[j] >> 15) * LANES + lane];
#pragma unroll
    for (int j = 0; j < 16; j++) {
      const float w = rec_norm(q[j]);
      half2_t v = __builtin_bit_cast(half2_t, vv[j]);
      acc0 = fmaf((float)v.x, w, acc0);
      acc1 = fmaf((float)v.y, w, acc1);
    }
  }
  for (; e + 8 <= re; e += 8) {
    uint4 r0 = *reinterpret_cast<const uint4*>(&edges[e]);
    uint4 r1 = *reinterpret_cast<const uint4*>(&edges[e + 4]);
    unsigned q[8] = {r0.x, r0.y, r0.z, r0.w, r1.x, r1.y, r1.z, r1.w};
    unsigned vv[8];
#pragma unroll
    for (int j = 0; j < 8; j++) vv[j] = hh[(q[j] >> 15) * LANES + lane];
#pragma unroll
    for (int j = 0; j < 8; j++) {
      const float w = rec_norm(q[j]);
      half2_t v = __builtin_bit_cast(half2_t, vv[j]);
      acc0 = fmaf((float)v.x, w, acc0);
      acc1 = fmaf((float)v.y, w, acc1);
    }
  }
  if (e < re) {
    uint4 r0 = *reinterpret_cast<const uint4*>(&edges[e]);
    unsigned q[4] = {r0.x, r0.y, r0.z, r0.w};
    unsigned vv[4];
#pragma unroll
    for (int j = 0; j < 4; j++) vv[j] = hh[(q[j] >> 15) * LANES + lane];
#pragma unroll
    for (int j = 0; j < 4; j++) {
      const float w = rec_norm(q[j]);
      half2_t v = __builtin_bit_cast(half2_t, vv[j]);
      acc0 = fmaf((float)v.x, w, acc0);
      acc1 = fmaf((float)v.y, w, acc1);
    }
  }
  tb[(unsigned)node * LANES + lane] = pack_bf16x2(acc0, acc1);
}

// ============================ GEMM: W-stationary in VGPRs, persistent blocks ============================

#define GB 521   // ceil(1563/3)

template <int K>
__global__ __launch_bounds__(256) void gemm_kernel(const unsigned short* __restrict__ A,
                                                   const unsigned short* __restrict__ Wt,
                                                   const float* __restrict__ bias,
                                                   unsigned short* __restrict__ out,
                                                   float* __restrict__ stats) {
  constexpr int KP = K + 8;
  __shared__ __align__(16) unsigned short sA[64 * KP];
  __shared__ float sS[128], sQ[128];
  const int tid = threadIdx.x;
  if (tid < 128) { sS[tid] = 0.f; sQ[tid] = 0.f; }
  const int wid = tid >> 6;
  const int lane = tid & 63;
  const int wrow = wid * 16;
  const int fr = lane & 15;
  const int fk = (lane >> 4) * 8;

  bf16x8 wfrag[8][K / 32];
#pragma unroll
  for (int cf = 0; cf < 8; cf++)
#pragma unroll
    for (int ks = 0; ks < K / 32; ks++)
      wfrag[cf][ks] = *reinterpret_cast<const bf16x8*>(&Wt[(size_t)(cf * 16 + fr) * K + ks * 32 + fk]);
  float bv[8];
#pragma unroll
  for (int cf = 0; cf < 8; cf++) bv[cf] = bias[cf * 16 + fr];

  constexpr int CPR = K / 8;
  const uint4* Ag = (const uint4*)A;
  const int orow = (lane >> 4) * 4;

  for (int pan = blockIdx.x; pan * 64 < NNODES; pan += GB) {
    const int row0 = pan * 64;
    __syncthreads();
#pragma unroll
    for (int i = tid; i < 64 * CPR; i += 256) {
      int row = i / CPR, ch = i % CPR;
      int grow = row0 + row;
      uint4 v = make_uint4(0u, 0u, 0u, 0u);
      if (grow < NNODES) v = Ag[(size_t)grow * CPR + ch];
      *reinterpret_cast<uint4*>(&sA[row * KP + ch * 8]) = v;
    }
    __syncthreads();

    f32x4 acc[8];
#pragma unroll
    for (int cf = 0; cf < 8; cf++) acc[cf] = (f32x4){0.f, 0.f, 0.f, 0.f};
    bf16x8 afrag[K / 32];
#pragma unroll
    for (int ks = 0; ks < K / 32; ks++)
      afrag[ks] = *reinterpret_cast<const bf16x8*>(&sA[(wrow + fr) * KP + ks * 32 + fk]);
#pragma unroll
    for (int cf = 0; cf < 8; cf++)
#pragma unroll
      for (int ks = 0; ks < K / 32; ks++)
        acc[cf] = __builtin_amdgcn_mfma_f32_16x16x32_bf16(afrag[ks], wfrag[cf][ks], acc[cf], 0, 0, 0);

#pragma unroll
    for (int cf = 0; cf < 8; cf++) {
      const int col = cf * 16 + fr;
      float s = 0.f, q = 0.f;
#pragma unroll
      for (int j = 0; j < 4; j++) {
        int grow = row0 + wrow + orow + j;
        float val = 0.f;
        if (grow < NNODES) {
          unsigned short o = bf16r(acc[cf][j] + bv[cf]);
          out[(size_t)grow * HID + col] = o;
          val = __uint_as_float((unsigned)o << 16);
        }
        s += val; q += val * val;
      }
      s += __shfl_xor(s, 16); s += __shfl_xor(s, 32);
      q += __shfl_xor(q, 16); q += __shfl_xor(q, 32);
      if (lane < 16) { atomicAdd(&sS[col], s); atomicAdd(&sQ[col], q); }
    }
  }
  __syncthreads();
  if (tid < 128) {
    atomicAdd(&stats[tid],       sS[tid]);
    atomicAdd(&stats[128 + tid], sQ[tid]);
  }
}

// ============================ BN apply (inline finalize): fh = relu(bn(h)) fp16 ============================

__global__ __launch_bounds__(256) void bnapply_kernel(const uint4* __restrict__ hb,
                                                      const float* __restrict__ stats,
                                                      const float* __restrict__ gamma,
                                                      const float* __restrict__ beta,
                                                      uint4* __restrict__ fh) {
  __shared__ float sc[128], sh[128];
  if (threadIdx.x < 128) {
    int c = threadIdx.x;
    float mu  = stats[c] * (1.0f / NNODES);
    float var = fmaf(-mu, mu, stats[128 + c] * (1.0f / NNODES));
    float scale = gamma[c] * rsqrtf(var + 1e-5f);
    sc[c] = scale;
    sh[c] = fmaf(-mu, scale, beta[c]);
  }
  __syncthreads();
  int i = blockIdx.x * 256 + threadIdx.x;   // grid exact: N*16/256
  uint4 v = hb[i];
  int cb = (i & 15) * 8;
  float r0 = fmaxf(fmaf(bf16lo(v.x), sc[cb + 0], sh[cb + 0]), 0.f);
  float r1 = fmaxf(fmaf(bf16hi(v.x), sc[cb + 1], sh[cb + 1]), 0.f);
  float r2 = fmaxf(fmaf(bf16lo(v.y), sc[cb + 2], sh[cb + 2]), 0.f);
  float r3 = fmaxf(fmaf(bf16hi(v.y), sc[cb + 3], sh[cb + 3]), 0.f);
  float r4 = fmaxf(fmaf(bf16lo(v.z), sc[cb + 4], sh[cb + 4]), 0.f);
  float r5 = fmaxf(fmaf(bf16hi(v.z), sc[cb + 5], sh[cb + 5]), 0.f);
  float r6 = fmaxf(fmaf(bf16lo(v.w), sc[cb + 6], sh[cb + 6]), 0.f);
  float r7 = fmaxf(fmaf(bf16hi(v.w), sc[cb + 7], sh[cb + 7]), 0.f);
  fh[i] = make_uint4(f16x2(r0, r1), f16x2(r2, r3), f16x2(r4, r5), f16x2(r6, r7));
}

// ============================ final BN (no ReLU) -> fp32 out ============================

__global__ __launch_bounds__(256) void normout_kernel(const unsigned* __restrict__ hb,
                                                      const float* __restrict__ stats,
                                                      const float* __restrict__ gamma,
                                                      const float* __restrict__ beta,
                                                      float2* __restrict__ out) {
  __shared__ float sc[128], sh[128];
  if (threadIdx.x < 128) {
    int c = threadIdx.x;
    float mu  = stats[c] * (1.0f / NNODES);
    float var = fmaf(-mu, mu, stats[128 + c] * (1.0f / NNODES));
    float scale = gamma[c] * rsqrtf(var + 1e-5f);
    sc[c] = scale;
    sh[c] = fmaf(-mu, scale, beta[c]);
  }
  __syncthreads();
  int i = blockIdx.x * 256 + threadIdx.x;   // grid exact: N*64/256
  unsigned u = hb[i];
  int c = (i & 63) * 2;
  out[i] = make_float2(fmaf(bf16lo(u), sc[c],     sh[c]),
                       fmaf(bf16hi(u), sc[c + 1], sh[c + 1]));
}

// ============================ launch ============================

extern "C" void kernel_launch(void* const* d_in, const int* in_sizes, int n_in,
                              void* d_out, int out_size, void* d_ws, size_t ws_size,
                              hipStream_t stream) {
  const float* x     = (const float*)d_in[0];
  const int*   ei    = (const int*)d_in[1];
  const float* ew    = (const float*)d_in[2];
  const float* W_in  = (const float*)d_in[3];
  const float* b_in  = (const float*)d_in[4];
  const float* W_mid = (const float*)d_in[5];
  const float* b_mid = (const float*)d_in[6];
  const float* W_out = (const float*)d_in[7];
  const float* b_out = (const float*)d_in[8];
  const float* gamma = (const float*)d_in[9];
  const float* beta  = (const float*)d_in[10];

  char* p = (char*)d_ws;
  auto alloc = [&](size_t bytes) -> char* {
    char* r = p;
    p += (bytes + 255) & ~(size_t)255;
    return r;
  };
  const size_t EPAD = (size_t)NEDGES + 3 * (size_t)NNODES + 32;
  unsigned* packed  = (unsigned*)alloc(8 * (size_t)NNODES * 4);  // [xcd][node], u32 packed
  float*    stats   = (float*)alloc(5 * 256 * 4);
  size_t zbytes = (size_t)(p - (char*)d_ws);          // only packed + stats zeroed
  unsigned* edges   = (unsigned*)alloc(EPAD * 4);                // 4B records; pads by scatter grid
  float*    dinv    = (float*)alloc((size_t)NNODES * 4);
  unsigned* row_ofs = (unsigned*)alloc((size_t)(NNODES + 1) * 4);
  uint4*    combo   = (uint4*)alloc((size_t)NNODES * 16);        // {rofs, xb0-3, xb4-7, tot}
  unsigned* bsums   = (unsigned*)alloc(512 * 4);
  unsigned short* rank = (unsigned short*)alloc((size_t)NEDGES * 2);
  unsigned* xh      = (unsigned*)alloc((size_t)NNODES * INDIM * 2);
  unsigned short* h = (unsigned short*)alloc((size_t)NNODES * HID * 2);
  unsigned short* t = (unsigned short*)alloc((size_t)NNODES * HID * 2);
  unsigned short* wt = (unsigned short*)alloc((size_t)WTOT * 2);
  uint4*    fh      = (uint4*)d_out;                  // fp16 f(h) scratch in d_out (25.6 of 51.2 MB)

  hipMemsetAsync(d_ws, 0, zbytes, stream);

  prep_kernel<<<EB + XB + WB, 256, 0, stream>>>(x, (uint2*)xh, W_in, W_mid, W_out, wt, ei, ew, packed, rank);
  scan1_kernel<<<NB, 256, 0, stream>>>(packed, row_ofs, bsums, dinv, combo);
  scan2_kernel<<<1, 512, 0, stream>>>(bsums, row_ofs, NB);
  scan3_kernel<<<NB, 256, 0, stream>>>(row_ofs, bsums, combo);
  scatter_kernel<<<EB + NB, 256, 0, stream>>>(ei, ew, dinv, rank, combo, edges);

  // layer 0: t = S·x ; h = t @ W_in + b_in (stats[0] fused)
  agg_kernel<32><<<(NNODES * 32) / 256, 256, 0, stream>>>(xh, row_ofs, edges, dinv, (unsigned*)t);
  gemm_kernel<INDIM><<<GB, 256, 0, stream>>>((const unsigned short*)t, wt, b_in, h, stats);

  // layers 1..4
  for (int l = 1; l <= 4; l++) {
    bnapply_kernel<<<(NNODES * 16) / 256, 256, 0, stream>>>((const uint4*)h, stats + (size_t)(l - 1) * 256,
                                                            gamma + (size_t)(l - 1) * HID,
                                                            beta + (size_t)(l - 1) * HID, fh);
    agg_kernel<64><<<(NNODES * 64) / 256, 256, 0, stream>>>((const unsigned*)fh, row_ofs, edges, dinv, (unsigned*)t);
    const float* b = (l <= 3) ? (b_mid + (size_t)(l - 1) * HID) : b_out;
    const unsigned short* wl = wt + HID * INDIM + (size_t)(l - 1) * HID * HID;
    gemm_kernel<HID><<<GB, 256, 0, stream>>>((const unsigned short*)t, wl, b, h, stats + (size_t)l * 256);
  }

  // final BN (no ReLU) on h4 -> d_out (fp32); fh region dead by now.
  normout_kernel<<<(NNODES * 64) / 256, 256, 0, stream>>>((const unsigned*)h, stats + 4 * 256,
                                                          gamma + 4 * HID, beta + 4 * HID, (float2*)d_out);
}